// Round 7
// baseline (690.444 us; speedup 1.0000x reference)
//
#include <hip/hip_runtime.h>
#include <hip/hip_fp16.h>

typedef unsigned short u16;
typedef float f32x4 __attribute__((ext_vector_type(4)));
typedef _Float16 half8 __attribute__((ext_vector_type(8)));
typedef unsigned short u16x4 __attribute__((ext_vector_type(4)));

#define CDIM 768
#define NP 1024
#define NB 32

static constexpr size_t CHW = (size_t)NB * CDIM * NP;  // 25,165,824

// workspace layout (bytes)
static constexpr size_t XT_OFF  = 0;                         // f16 [b][p][c]; later reused as aoT f16
static constexpr size_t HS_OFF  = CHW * 2;                   // fp32 hs11, hs111 (2*CHW*4)
static constexpr size_t WHI_OFF = HS_OFF + CHW * 8;          // f16 weights

__device__ __forceinline__ u16 f16bits(float f) {
  return __half_as_ushort(__float2half_rn(f));
}

typedef __attribute__((address_space(1))) void gv_t;
typedef __attribute__((address_space(3))) void lv_t;
__device__ __forceinline__ void gload_lds16(const void* g, void* l) {
  __builtin_amdgcn_global_load_lds((gv_t*)g, (lv_t*)l, 16, 0, 0);
}

// ---------------- cast W (fp32 -> f16) ----------------
__global__ __launch_bounds__(256) void cast_w_k(const float* __restrict__ W,
                                                u16* __restrict__ hi) {
  int i = blockIdx.x * 256 + threadIdx.x;
  float4 v = ((const float4*)W)[i];
  u16x4 h4 = {f16bits(v.x), f16bits(v.y), f16bits(v.z), f16bits(v.w)};
  ((u16x4*)hi)[i] = h4;
}

// ---------------- transpose + f16 cast: src fp32 [b][c][p] -> dst f16 [b][p][c] ----------------
__global__ __launch_bounds__(256) void transpose_f16_k(const float* __restrict__ src,
                                                       u16* __restrict__ dxt) {
  __shared__ float tle[32][33];
  const int b = blockIdx.z, c0 = blockIdx.y * 32, p0 = blockIdx.x * 32;
  const int tid = threadIdx.x;
  const int lr = tid >> 5, lc = tid & 31;
  const float* s = src + ((size_t)b * CDIM + c0) * NP + p0;
#pragma unroll
  for (int it = 0; it < 4; ++it) {
    int c = it * 8 + lr;
    tle[c][lc] = s[(size_t)c * NP + lc];
  }
  __syncthreads();
#pragma unroll
  for (int it = 0; it < 4; ++it) {
    int p = it * 8 + lr;
    float v = tle[lc][p];
    size_t off = ((size_t)b * NP + p0 + p) * CDIM + c0 + lc;
    dxt[off] = f16bits(v);
  }
}

// ---------------- spatial permutations ----------------
__device__ __forceinline__ int sigma_fn(int mode, int z, int t, int p) {
  if (t == 0 || mode == 1) return p;
  int i = p >> 5, j = p & 31;
  if (z == 0) {
    if (t == 1) return (j << 5) | (31 - i);
    if (t == 2) return ((31 - i) << 5) | (31 - j);
    return ((31 - j) << 5) | i;
  } else {
    int ib = i & 16, jb = j & 16, il = i & 15, jl = j & 15;
    if (t == 1) return ((ib | jl) << 5) | (jb | (15 - il));
    if (t == 2) return ((ib | (15 - il)) << 5) | (jb | (15 - jl));
    return ((ib | (15 - jl)) << 5) | (jb | il);
  }
}

// ---------------- pipelined multi-term f16 GEMM, occupancy-first ----------------
// Tile 128(o) x 128(p), 512 threads (8 waves, 2Mx4N, wave tile 64x32), BK=32.
// 3 LDS buffers x 16KB (A [0,4096) u16: [128 rows][4 chunks of 8 u16], 64B stride,
// phys = logical ^ ((row>>1)&3); B [4096,8192) identical geometry) -> 48KB total.
// Depth-2 prefetch, counted vmcnt(2)/step (2 loads/thread/step), 1 barrier/step.
// VGPR <=128 via launch_bounds(512,4): targets 2 blocks/CU = 16 waves (4/SIMD).
__global__ __launch_bounds__(512, 4) void gemm_p(
    const u16* __restrict__ Whi,
    const u16* __restrict__ Bx,
    const float* __restrict__ bias, float* __restrict__ dst,
    int nterms, int wselBase, int mode) {
  extern __shared__ u16 lds[];  // 3 x 8192 u16
  const int tid = threadIdx.x;
  const int lane = tid & 63;
  const int w = tid >> 6;
  const int wr = w >> 2, wc = w & 3;
  const int z = blockIdx.z;
  const int b = blockIdx.x >> 3;
  const int p0 = (blockIdx.x & 7) << 7;
  const int o0 = blockIdx.y << 7;
  const int l15 = lane & 15, l4 = lane >> 4;

  float* dstz = dst + (size_t)z * CHW;
  const int NSTEP = nterms * 24;

  // LDS read bases (u16 units); frag m: +m*512, frag n: +n*512 (XOR invariant under +16 rows)
  const int rA = wr * 64 + l15;
  const int baseA = rA * 32 + (l4 ^ ((rA >> 1) & 3)) * 8;
  const int rB = wc * 32 + l15;
  const int baseB = 4096 + rB * 32 + (l4 ^ ((rB >> 1) & 3)) * 8;

  // staging decode: 512 slots each for A and B, identical mapping
  const int arow = tid >> 2;
  const int acof = ((tid & 3) ^ ((arow >> 1) & 3)) * 8;
  const int adst = tid * 8;
  const int bdst = 4096 + tid * 8;

  const u16* aptr;
  const u16* bptr;
  int nsk = 0, nst = 0;
  auto setPtrs = [&](int term) {
    int wsel = wselBase + z * 4 + term;
    aptr = Whi + ((size_t)wsel * CDIM + o0 + arow) * CDIM + acof;
    int srow = sigma_fn(mode, z, term, p0 + arow);
    bptr = Bx + ((size_t)b * NP + srow) * CDIM + acof;
  };
  auto stageTo = [&](int wb) {
    u16* lw = lds + wb * 8192;
    gload_lds16(aptr, lw + adst);
    gload_lds16(bptr, lw + bdst);
    aptr += 32; bptr += 32;
    ++nsk;
  };

  f32x4 acc[4][2], racc[4][2];
#pragma unroll
  for (int m = 0; m < 4; ++m)
#pragma unroll
    for (int n = 0; n < 2; ++n) {
      acc[m][n] = (f32x4){0.f, 0.f, 0.f, 0.f};
      racc[m][n] = (f32x4){0.f, 0.f, 0.f, 0.f};
    }
  float4 bvm[4];

  // prologue: stage steps 0,1 into bufs 0,1
  setPtrs(0);
  stageTo(0);
  stageTo(1);

  int cur = 0, wb = 2;
  int ckk = 0, cterm = 0;

  for (int s = 0; s < NSTEP; ++s) {
    if (s + 1 < NSTEP) {
      asm volatile("s_waitcnt vmcnt(2)" ::: "memory");
    } else {
      asm volatile("s_waitcnt vmcnt(0)" ::: "memory");
    }
    __builtin_amdgcn_s_barrier();
    asm volatile("" ::: "memory");

    const u16* la = lds + cur * 8192;

    if (ckk == 0) {
      int wsel = wselBase + z * 4 + cterm;
#pragma unroll
      for (int m = 0; m < 4; ++m)
        bvm[m] = *(const float4*)&bias[wsel * CDIM + o0 + wr * 64 + m * 16 + l4 * 4];
    }

    half8 ah[4], bb[2];
#pragma unroll
    for (int m = 0; m < 4; ++m) ah[m] = *(const half8*)(la + baseA + m * 512);
#pragma unroll
    for (int n = 0; n < 2; ++n) bb[n] = *(const half8*)(la + baseB + n * 512);

    if (s + 2 < NSTEP) {
      if (nsk == 24) { ++nst; nsk = 0; setPtrs(nst); }
      stageTo(wb);
    }

    asm volatile("s_waitcnt lgkmcnt(0)" ::: "memory");
    __builtin_amdgcn_s_setprio(1);
#pragma unroll
    for (int m = 0; m < 4; ++m)
#pragma unroll
      for (int n = 0; n < 2; ++n)
        acc[m][n] = __builtin_amdgcn_mfma_f32_16x16x32_f16(ah[m], bb[n], acc[m][n], 0, 0, 0);
    __builtin_amdgcn_s_setprio(0);

    if (ckk == 23) {  // term boundary: relu(acc + bias) -> racc, reset acc
#pragma unroll
      for (int m = 0; m < 4; ++m) {
        float bvf[4] = {bvm[m].x, bvm[m].y, bvm[m].z, bvm[m].w};
#pragma unroll
        for (int n = 0; n < 2; ++n)
#pragma unroll
          for (int r = 0; r < 4; ++r) {
            racc[m][n][r] += fmaxf(0.f, acc[m][n][r] + bvf[r]);
            acc[m][n][r] = 0.f;
          }
      }
    }
    cur = cur == 2 ? 0 : cur + 1;
    wb = wb == 2 ? 0 : wb + 1;
    ++ckk; if (ckk == 24) { ckk = 0; ++cterm; }
  }

  // C write: row = o0+wr*64+m*16+l4*4+r, col = p0+wc*32+n*16+l15
#pragma unroll
  for (int m = 0; m < 4; ++m) {
    int rowb = o0 + wr * 64 + m * 16 + l4 * 4;
#pragma unroll
    for (int n = 0; n < 2; ++n) {
      int col = p0 + wc * 32 + n * 16 + l15;
      float* dp = dstz + ((size_t)b * CDIM + rowb) * NP + col;
#pragma unroll
      for (int r = 0; r < 4; ++r) dp[(size_t)r * NP] = racc[m][n][r];
    }
  }
}

// ---------------- per-(b,c) 32x32 attention, fp32, fused transposed-f16 output ----------------
__global__ __launch_bounds__(256) void attn_f_k(const float* __restrict__ hs, u16* __restrict__ aoT) {
  __shared__ float q[4][1056];   // pitch 33
  __shared__ float kk[4][1056];
  const int tid = threadIdx.x, w = tid >> 6, lane = tid & 63;
  const int pair0 = blockIdx.x * 4;
  const int b = pair0 / CDIM;
  const int c0 = pair0 % CDIM;
#pragma unroll
  for (int it = 0; it < 8; ++it) {
    int d4 = it * 256 + tid;
    int pr = d4 >> 9;
    int mat = (d4 >> 8) & 1;
    int off4 = d4 & 255;
    float4 v = *(const float4*)&hs[(size_t)mat * CHW + (size_t)(pair0 + pr) * NP + off4 * 4];
    float* dl = mat ? kk[pr] : q[pr];
    int off = off4 * 4;
    int base = (off >> 5) * 33 + (off & 31);
    dl[base] = v.x; dl[base + 1] = v.y; dl[base + 2] = v.z; dl[base + 3] = v.w;
  }
  __syncthreads();
  const int i = lane & 31, half = lane >> 5, jb = half * 16;
  const float* Q = q[w];
  const float* K = kk[w];
  float qr[32];
#pragma unroll
  for (int tt = 0; tt < 32; ++tt) qr[tt] = Q[i * 33 + tt];
  float a[16];
#pragma unroll
  for (int j = 0; j < 16; ++j) {
    float s = 0.f;
#pragma unroll
    for (int tt = 0; tt < 32; ++tt) s = fmaf(qr[tt], K[tt * 33 + jb + j], s);
    a[j] = s;
  }
  float mx = a[0];
#pragma unroll
  for (int j = 1; j < 16; ++j) mx = fmaxf(mx, a[j]);
  mx = fmaxf(mx, __shfl_xor(mx, 32));
  float ssum = 0.f;
#pragma unroll
  for (int j = 0; j < 16; ++j) { a[j] = expf(a[j] - mx); ssum += a[j]; }
  ssum += __shfl_xor(ssum, 32);
  float inv = 1.f / ssum;
#pragma unroll
  for (int j = 0; j < 16; ++j) a[j] *= inv;
#pragma unroll
  for (int h = 0; h < 32; ++h) {
    float o = 0.f;
#pragma unroll
    for (int j = 0; j < 16; ++j) o = fmaf(a[j], Q[(jb + j) * 33 + h], o);
    o += __shfl_xor(o, 32);
    if (half == (h >> 4)) kk[w][i * 33 + h] = o;
  }
  __syncthreads();
#pragma unroll
  for (int it = 0; it < 4; ++it) {
    int p = it * 256 + tid;
    int base = (p >> 5) * 33 + (p & 31);
    ushort4 v;
    v.x = f16bits(kk[0][base]);
    v.y = f16bits(kk[1][base]);
    v.z = f16bits(kk[2][base]);
    v.w = f16bits(kk[3][base]);
    *(ushort4*)&aoT[((size_t)b * NP + p) * CDIM + c0] = v;
  }
}

extern "C" void kernel_launch(void* const* d_in, const int* in_sizes, int n_in,
                              void* d_out, int out_size, void* d_ws, size_t ws_size,
                              hipStream_t stream) {
  (void)in_sizes; (void)n_in; (void)out_size; (void)ws_size;
  const float* x = (const float*)d_in[0];
  const float* Ws = (const float*)d_in[1];
  const float* bs = (const float*)d_in[2];
  float* out = (float*)d_out;
  char* ws = (char*)d_ws;

  u16* XT  = (u16*)(ws + XT_OFF);
  float* hs = (float*)(ws + HS_OFF);
  u16* Whi = (u16*)(ws + WHI_OFF);
  u16* aoT = (u16*)(ws + XT_OFF);   // aliases XT (dead after stage-1)

  cast_w_k<<<5184, 256, 0, stream>>>(Ws, Whi);
  transpose_f16_k<<<dim3(32, 24, 32), 256, 0, stream>>>(x, XT);
  // stage-1: hs11 (z=0, W0..3) and hs111 (z=1, W4..7); 128x128 tiles
  gemm_p<<<dim3(256, 6, 2), 512, 49152, stream>>>(Whi, XT, bs, hs, 4, 0, 0);
  attn_f_k<<<6144, 256, 0, stream>>>(hs, aoT);
  // final conv: relu(W8 @ attout + b8) -> d_out
  gemm_p<<<dim3(256, 6, 1), 512, 49152, stream>>>(Whi, aoT, bs, out, 1, 8, 1);
}

// Round 8
// 569.668 us; speedup vs baseline: 1.2120x; 1.2120x over previous
//
#include <hip/hip_runtime.h>
#include <hip/hip_fp16.h>

typedef unsigned short u16;
typedef float f32x4 __attribute__((ext_vector_type(4)));
typedef _Float16 half8 __attribute__((ext_vector_type(8)));
typedef unsigned short u16x4 __attribute__((ext_vector_type(4)));

#define CDIM 768
#define NP 1024
#define NB 32

static constexpr size_t CHW = (size_t)NB * CDIM * NP;  // 25,165,824

// workspace layout (bytes)
static constexpr size_t XT_OFF  = 0;                         // f16 [b][p][c]; later reused as aoT f16
static constexpr size_t HS_OFF  = CHW * 2;                   // f16 hs11, hs111 (2*CHW*2)
static constexpr size_t WHI_OFF = HS_OFF + CHW * 4;          // f16 weights

__device__ __forceinline__ u16 f16bits(float f) {
  return __half_as_ushort(__float2half_rn(f));
}
__device__ __forceinline__ float f16tof(u16 b) {
  __half_raw hr; hr.x = b; return __half2float(__half(hr));
}

typedef __attribute__((address_space(1))) void gv_t;
typedef __attribute__((address_space(3))) void lv_t;
__device__ __forceinline__ void gload_lds16(const void* g, void* l) {
  __builtin_amdgcn_global_load_lds((gv_t*)g, (lv_t*)l, 16, 0, 0);
}

// ---------------- cast W (fp32 -> f16) ----------------
__global__ __launch_bounds__(256) void cast_w_k(const float* __restrict__ W,
                                                u16* __restrict__ hi) {
  int i = blockIdx.x * 256 + threadIdx.x;
  float4 v = ((const float4*)W)[i];
  u16x4 h4 = {f16bits(v.x), f16bits(v.y), f16bits(v.z), f16bits(v.w)};
  ((u16x4*)hi)[i] = h4;
}

// ---------------- transpose + f16 cast: src fp32 [b][c][p] -> dst f16 [b][p][c] ----------------
__global__ __launch_bounds__(256) void transpose_f16_k(const float* __restrict__ src,
                                                       u16* __restrict__ dxt) {
  __shared__ float tle[32][33];
  const int b = blockIdx.z, c0 = blockIdx.y * 32, p0 = blockIdx.x * 32;
  const int tid = threadIdx.x;
  const int lr = tid >> 5, lc = tid & 31;
  const float* s = src + ((size_t)b * CDIM + c0) * NP + p0;
#pragma unroll
  for (int it = 0; it < 4; ++it) {
    int c = it * 8 + lr;
    tle[c][lc] = s[(size_t)c * NP + lc];
  }
  __syncthreads();
#pragma unroll
  for (int it = 0; it < 4; ++it) {
    int p = it * 8 + lr;
    float v = tle[lc][p];
    size_t off = ((size_t)b * NP + p0 + p) * CDIM + c0 + lc;
    dxt[off] = f16bits(v);
  }
}

// ---------------- spatial permutations ----------------
__device__ __forceinline__ int sigma_fn(int mode, int z, int t, int p) {
  if (t == 0 || mode == 1) return p;
  int i = p >> 5, j = p & 31;
  if (z == 0) {
    if (t == 1) return (j << 5) | (31 - i);
    if (t == 2) return ((31 - i) << 5) | (31 - j);
    return ((31 - j) << 5) | i;
  } else {
    int ib = i & 16, jb = j & 16, il = i & 15, jl = j & 15;
    if (t == 1) return ((ib | jl) << 5) | (jb | (15 - il));
    if (t == 2) return ((ib | (15 - il)) << 5) | (jb | (15 - jl));
    return ((ib | (15 - jl)) << 5) | (jb | il);
  }
}

// ---------------- pipelined multi-term f16 GEMM, BK=64, 3-buffer depth-2 counted vmcnt ----------------
// Tile 128(o) x 256(p), 512 threads (8 waves, 2Mx4N, wave tile 64x64), BK=64.
// Per LDS buffer (24576 u16 = 48KB): A [0,8192): [128 rows][8 chunks of 8 u16], 128B stride,
// phys = logical ^ (row&7); B [8192,24576): 2 k-halves x [256 rows][4 chunks], 64B stride,
// phys = logical ^ ((row>>1)&3). 3 buffers + 2KB bias = 149.5KB LDS.
// 6 loads/thread/step; steady-state wait = vmcnt(6) (next step's 6 stay in flight).
template <int OUTF16>
__global__ __launch_bounds__(512, 2) void gemm_p(
    const u16* __restrict__ Whi,
    const u16* __restrict__ Bx,
    const float* __restrict__ bias, void* __restrict__ dst,
    int nterms, int wselBase, int mode) {
  extern __shared__ u16 lds[];  // 3 x 24576 u16 + 512 f32 bias
  const int tid = threadIdx.x;
  const int lane = tid & 63;
  const int w = tid >> 6;
  const int wr = w >> 2, wc = w & 3;
  const int z = blockIdx.z;
  const int b = blockIdx.x >> 2;
  const int p0 = (blockIdx.x & 3) << 8;
  const int o0 = blockIdx.y << 7;
  const int l15 = lane & 15, l4 = lane >> 4;
  const int s7 = l15 & 7;
  float* blds = (float*)(lds + 73728);

  const int NSTEP = nterms * 12;

  // LDS read bases (u16 units); A frag m: +m*1024, B frag n: +n*512
  const int baseA0 = (wr * 64 + l15) * 64 + ((l4) ^ s7) * 8;
  const int baseA1 = (wr * 64 + l15) * 64 + ((4 + l4) ^ s7) * 8;
  const int baseB0 = 8192 + (wc * 64 + l15) * 32 + (l4 ^ ((l15 >> 1) & 3)) * 8;
  const int baseB1 = baseB0 + 8192;

  // staging decode (per-thread constants)
  int arow[2], acof[2];
#pragma unroll
  for (int it = 0; it < 2; ++it) {
    int d = it * 512 + tid;
    arow[it] = d >> 3;
    acof[it] = ((d & 7) ^ (arow[it] & 7)) * 8;
  }
  int brow[4], bcof[4];
#pragma unroll
  for (int it = 0; it < 4; ++it) {
    int d = it * 512 + tid;
    int h = d >> 10, rem = d & 1023;
    brow[it] = rem >> 2;
    bcof[it] = h * 32 + (((rem & 3) ^ ((brow[it] >> 1) & 3))) * 8;
  }

  const u16* aptr[2];
  const u16* bptr[4];
  auto setPtrs = [&](int term) {
    int wsel = wselBase + z * 4 + term;
#pragma unroll
    for (int it = 0; it < 2; ++it)
      aptr[it] = Whi + ((size_t)wsel * CDIM + o0 + arow[it]) * CDIM + acof[it];
#pragma unroll
    for (int it = 0; it < 4; ++it) {
      int srow = sigma_fn(mode, z, term, p0 + brow[it]);
      bptr[it] = Bx + ((size_t)b * NP + srow) * CDIM + bcof[it];
    }
  };

  // bias -> LDS (before any staging so its vmcnt drains first)
  if (tid < nterms * 128) {
    int t = tid >> 7, oo = tid & 127;
    blds[tid] = bias[(size_t)(wselBase + z * 4 + t) * CDIM + o0 + oo];
  }
  asm volatile("s_waitcnt lgkmcnt(0)" ::: "memory");

  f32x4 acc[4][4], racc[4][4];
#pragma unroll
  for (int m = 0; m < 4; ++m)
#pragma unroll
    for (int n = 0; n < 4; ++n) {
      acc[m][n] = (f32x4){0.f, 0.f, 0.f, 0.f};
      racc[m][n] = (f32x4){0.f, 0.f, 0.f, 0.f};
    }

  // prologue: stage steps 0,1 into bufs 0,1
  setPtrs(0);
#pragma unroll
  for (int it = 0; it < 2; ++it) gload_lds16(aptr[it], lds + (it * 512 + tid) * 8);
#pragma unroll
  for (int it = 0; it < 4; ++it) gload_lds16(bptr[it], lds + 8192 + (it * 512 + tid) * 8);
#pragma unroll
  for (int it = 0; it < 2; ++it) aptr[it] += 64;
#pragma unroll
  for (int it = 0; it < 4; ++it) bptr[it] += 64;
#pragma unroll
  for (int it = 0; it < 2; ++it) gload_lds16(aptr[it], lds + 24576 + (it * 512 + tid) * 8);
#pragma unroll
  for (int it = 0; it < 4; ++it) gload_lds16(bptr[it], lds + 24576 + 8192 + (it * 512 + tid) * 8);
#pragma unroll
  for (int it = 0; it < 2; ++it) aptr[it] += 64;
#pragma unroll
  for (int it = 0; it < 4; ++it) bptr[it] += 64;

  int nsk = 2, nst = 0;        // staged-step count in current term / its term
  int ckk = 0, cterm = 0;      // consumed k-step / term
  int cur = 0, wb = 2;

  for (int s = 0; s < NSTEP; ++s) {
    if (s + 1 < NSTEP) {
      asm volatile("s_waitcnt vmcnt(6)" ::: "memory");
    } else {
      asm volatile("s_waitcnt vmcnt(0)" ::: "memory");
    }
    __builtin_amdgcn_s_barrier();
    asm volatile("" ::: "memory");

    const u16* la = lds + cur * 24576;
    u16* ldst = lds + wb * 24576;
    const bool dostage = (s + 2) < NSTEP;
    if (dostage && nsk == 12) { ++nst; nsk = 0; setPtrs(nst); }

    half8 ah[4], bb[4];
    // ======== phase 0 (k-half 0): ds_read; stage A(s+2); 16 MFMA ========
#pragma unroll
    for (int m = 0; m < 4; ++m) ah[m] = *(const half8*)(la + baseA0 + m * 1024);
#pragma unroll
    for (int n = 0; n < 4; ++n) bb[n] = *(const half8*)(la + baseB0 + n * 512);
    if (dostage) {
#pragma unroll
      for (int it = 0; it < 2; ++it) gload_lds16(aptr[it], ldst + (it * 512 + tid) * 8);
    }
    asm volatile("s_waitcnt lgkmcnt(0)" ::: "memory");
    __builtin_amdgcn_s_setprio(1);
#pragma unroll
    for (int m = 0; m < 4; ++m)
#pragma unroll
      for (int n = 0; n < 4; ++n)
        acc[m][n] = __builtin_amdgcn_mfma_f32_16x16x32_f16(ah[m], bb[n], acc[m][n], 0, 0, 0);
    __builtin_amdgcn_s_setprio(0);

    // ======== phase 1 (k-half 1): ds_read; stage B(s+2); 16 MFMA ========
#pragma unroll
    for (int m = 0; m < 4; ++m) ah[m] = *(const half8*)(la + baseA1 + m * 1024);
#pragma unroll
    for (int n = 0; n < 4; ++n) bb[n] = *(const half8*)(la + baseB1 + n * 512);
    if (dostage) {
#pragma unroll
      for (int it = 0; it < 4; ++it) gload_lds16(bptr[it], ldst + 8192 + (it * 512 + tid) * 8);
#pragma unroll
      for (int it = 0; it < 2; ++it) aptr[it] += 64;
#pragma unroll
      for (int it = 0; it < 4; ++it) bptr[it] += 64;
      ++nsk;
    }
    asm volatile("s_waitcnt lgkmcnt(0)" ::: "memory");
    __builtin_amdgcn_s_setprio(1);
#pragma unroll
    for (int m = 0; m < 4; ++m)
#pragma unroll
      for (int n = 0; n < 4; ++n)
        acc[m][n] = __builtin_amdgcn_mfma_f32_16x16x32_f16(ah[m], bb[n], acc[m][n], 0, 0, 0);
    __builtin_amdgcn_s_setprio(0);

    if (ckk == 11) {  // term boundary: relu(acc + bias) -> racc, reset acc
#pragma unroll
      for (int m = 0; m < 4; ++m) {
        float4 bv = *(const float4*)&blds[cterm * 128 + wr * 64 + m * 16 + l4 * 4];
        float bvf[4] = {bv.x, bv.y, bv.z, bv.w};
#pragma unroll
        for (int n = 0; n < 4; ++n)
#pragma unroll
          for (int r = 0; r < 4; ++r) {
            racc[m][n][r] += fmaxf(0.f, acc[m][n][r] + bvf[r]);
            acc[m][n][r] = 0.f;
          }
      }
    }
    cur = cur == 2 ? 0 : cur + 1;
    wb = wb == 2 ? 0 : wb + 1;
    ++ckk; if (ckk == 12) { ckk = 0; ++cterm; }
  }

  // C write: row = o0+wr*64+m*16+l4*4+r, col = p0+wc*64+n*16+l15
#pragma unroll
  for (int m = 0; m < 4; ++m) {
    int rowb = o0 + wr * 64 + m * 16 + l4 * 4;
#pragma unroll
    for (int n = 0; n < 4; ++n) {
      int col = p0 + wc * 64 + n * 16 + l15;
      size_t base = ((size_t)b * CDIM + rowb) * NP + col;
      if (OUTF16) {
        u16* dp = (u16*)dst + (size_t)z * CHW + base;
#pragma unroll
        for (int r = 0; r < 4; ++r) dp[(size_t)r * NP] = f16bits(racc[m][n][r]);
      } else {
        float* dp = (float*)dst + (size_t)z * CHW + base;
#pragma unroll
        for (int r = 0; r < 4; ++r) dp[(size_t)r * NP] = racc[m][n][r];
      }
    }
  }
}

// ---------------- per-(b,c) 32x32 attention, f16 in, fused transposed-f16 output ----------------
__global__ __launch_bounds__(256) void attn_f_k(const u16* __restrict__ hs, u16* __restrict__ aoT) {
  __shared__ float q[4][1056];   // pitch 33
  __shared__ float kk[4][1056];
  const int tid = threadIdx.x, w = tid >> 6, lane = tid & 63;
  const int pair0 = blockIdx.x * 4;
  const int b = pair0 / CDIM;
  const int c0 = pair0 % CDIM;
#pragma unroll
  for (int it = 0; it < 8; ++it) {
    int d4 = it * 256 + tid;
    int pr = d4 >> 9;
    int mat = (d4 >> 8) & 1;
    int off4 = d4 & 255;
    ushort4 hv = *(const ushort4*)&hs[(size_t)mat * CHW + (size_t)(pair0 + pr) * NP + off4 * 4];
    float* dl = mat ? kk[pr] : q[pr];
    int off = off4 * 4;
    int base = (off >> 5) * 33 + (off & 31);
    dl[base] = f16tof(hv.x); dl[base + 1] = f16tof(hv.y);
    dl[base + 2] = f16tof(hv.z); dl[base + 3] = f16tof(hv.w);
  }
  __syncthreads();
  const int i = lane & 31, half = lane >> 5, jb = half * 16;
  const float* Q = q[w];
  const float* K = kk[w];
  float qr[32];
#pragma unroll
  for (int tt = 0; tt < 32; ++tt) qr[tt] = Q[i * 33 + tt];
  float a[16];
#pragma unroll
  for (int j = 0; j < 16; ++j) {
    float s = 0.f;
#pragma unroll
    for (int tt = 0; tt < 32; ++tt) s = fmaf(qr[tt], K[tt * 33 + jb + j], s);
    a[j] = s;
  }
  float mx = a[0];
#pragma unroll
  for (int j = 1; j < 16; ++j) mx = fmaxf(mx, a[j]);
  mx = fmaxf(mx, __shfl_xor(mx, 32));
  float ssum = 0.f;
#pragma unroll
  for (int j = 0; j < 16; ++j) { a[j] = expf(a[j] - mx); ssum += a[j]; }
  ssum += __shfl_xor(ssum, 32);
  float inv = 1.f / ssum;
#pragma unroll
  for (int j = 0; j < 16; ++j) a[j] *= inv;
#pragma unroll
  for (int h = 0; h < 32; ++h) {
    float o = 0.f;
#pragma unroll
    for (int j = 0; j < 16; ++j) o = fmaf(a[j], Q[(jb + j) * 33 + h], o);
    o += __shfl_xor(o, 32);
    if (half == (h >> 4)) kk[w][i * 33 + h] = o;
  }
  __syncthreads();
#pragma unroll
  for (int it = 0; it < 4; ++it) {
    int p = it * 256 + tid;
    int base = (p >> 5) * 33 + (p & 31);
    ushort4 v;
    v.x = f16bits(kk[0][base]);
    v.y = f16bits(kk[1][base]);
    v.z = f16bits(kk[2][base]);
    v.w = f16bits(kk[3][base]);
    *(ushort4*)&aoT[((size_t)b * NP + p) * CDIM + c0] = v;
  }
}

extern "C" void kernel_launch(void* const* d_in, const int* in_sizes, int n_in,
                              void* d_out, int out_size, void* d_ws, size_t ws_size,
                              hipStream_t stream) {
  (void)in_sizes; (void)n_in; (void)out_size; (void)ws_size;
  const float* x = (const float*)d_in[0];
  const float* Ws = (const float*)d_in[1];
  const float* bs = (const float*)d_in[2];
  float* out = (float*)d_out;
  char* ws = (char*)d_ws;

  u16* XT  = (u16*)(ws + XT_OFF);
  u16* hs  = (u16*)(ws + HS_OFF);    // f16 hs11 (z0), hs111 (z1)
  u16* Whi = (u16*)(ws + WHI_OFF);
  u16* aoT = (u16*)(ws + XT_OFF);    // aliases XT (dead after stage-1)

  cast_w_k<<<5184, 256, 0, stream>>>(Ws, Whi);
  transpose_f16_k<<<dim3(32, 24, 32), 256, 0, stream>>>(x, XT);
  // stage-1: hs11 (z=0, W0..3) and hs111 (z=1, W4..7); 128x256 tiles, f16 output
  gemm_p<1><<<dim3(128, 6, 2), 512, 149504, stream>>>(Whi, XT, bs, (void*)hs, 4, 0, 0);
  attn_f_k<<<6144, 256, 0, stream>>>(hs, aoT);
  // final conv: relu(W8 @ attout + b8) -> d_out (fp32)
  gemm_p<0><<<dim3(128, 6, 1), 512, 149504, stream>>>(Whi, aoT, bs, (void*)out, 1, 8, 1);
}